// Round 1
// baseline (1197.518 us; speedup 1.0000x reference)
//
#include <hip/hip_runtime.h>
#include <math.h>

#define HSTEP 0.1f
#define EPS_IN 1e-5f
#define BIGF 1e10f
#define DCF 3.79f

// ---------------------------------------------------------------------------
// helpers
// ---------------------------------------------------------------------------
__device__ inline float block_sum(float v, float* sred) {
    // wave (64-lane) reduction then cross-wave via LDS
    #pragma unroll
    for (int off = 32; off > 0; off >>= 1) v += __shfl_down(v, off);
    int wid = threadIdx.x >> 6;
    int nw  = blockDim.x >> 6;
    if ((threadIdx.x & 63) == 0) sred[wid] = v;
    __syncthreads();
    float total = 0.f;
    for (int i = 0; i < nw; ++i) total += sred[i];
    __syncthreads();   // allow sred reuse
    return total;
}

// ---------------------------------------------------------------------------
// fused conv (optionally transposed weights) * mask -> masked instance norm
// -> relu -> optional skip add.  One block per (b, co).
// ---------------------------------------------------------------------------
template<bool TR>
__global__ void __launch_bounds__(256)
conv_in_relu_kernel(const float* __restrict__ xin, float* __restrict__ out,
                    const float* __restrict__ K, int Cin, int Cout, int N,
                    const float* __restrict__ mask, const float* __restrict__ denom,
                    const float* __restrict__ skip)
{
    __shared__ float srow[2048];
    __shared__ float swt[128 * 3];
    __shared__ float sred[8];

    const int b   = blockIdx.x / Cout;
    const int co  = blockIdx.x % Cout;
    const int tid = threadIdx.x;

    for (int i = tid; i < Cin * 3; i += blockDim.x) {
        int ci = i / 3, k = i % 3;
        swt[i] = TR ? K[((size_t)ci * Cout + co) * 3 + (2 - k)]
                    : K[((size_t)co * Cin + ci) * 3 + k];
    }
    __syncthreads();

    const float* mrow = mask + (size_t)b * N;
    float lsum = 0.f;
    for (int n = tid; n < N; n += blockDim.x) {
        float acc = 0.f;
        const float* xr = xin + (size_t)b * Cin * N + n;
        for (int ci = 0; ci < Cin; ++ci, xr += N) {
            float xm = (n > 0)     ? xr[-1] : 0.f;
            float x0 = xr[0];
            float xp = (n < N - 1) ? xr[1]  : 0.f;
            acc = fmaf(swt[ci * 3 + 0], xm, acc);
            acc = fmaf(swt[ci * 3 + 1], x0, acc);
            acc = fmaf(swt[ci * 3 + 2], xp, acc);
        }
        float v = acc * mrow[n];
        srow[n] = v;
        lsum += v;
    }
    float dn   = denom[b];
    float mean = block_sum(lsum, sred) / dn;

    float lss = 0.f;
    for (int n = tid; n < N; n += blockDim.x) {
        float mk = mrow[n];
        float w  = (srow[n] - mean * mk) * mk;
        lss += w * w;
    }
    float var = block_sum(lss, sred) / dn;
    float inv = 1.f / sqrtf(var + EPS_IN);

    float* orow = out + ((size_t)b * Cout + co) * N;
    const float* skrow = skip ? skip + ((size_t)b * Cout + co) * N : nullptr;
    for (int n = tid; n < N; n += blockDim.x) {
        float mk = mrow[n];
        float zv = (srow[n] - mean * mk) * inv;
        float r  = fmaxf(zv, 0.f);
        if (skrow) r += skrow[n];
        orow[n] = r;
    }
}

// ---------------------------------------------------------------------------
// residual update: xc -= HSTEP * conv(z) * mask   (conv optionally transposed)
// ---------------------------------------------------------------------------
template<bool TR>
__global__ void __launch_bounds__(256)
conv_axpy_kernel(const float* __restrict__ z, float* __restrict__ xc,
                 const float* __restrict__ K, int Cin, int Cout, int N,
                 const float* __restrict__ mask)
{
    __shared__ float swt[128 * 3];
    const int b   = blockIdx.x / Cout;
    const int co  = blockIdx.x % Cout;
    const int tid = threadIdx.x;

    for (int i = tid; i < Cin * 3; i += blockDim.x) {
        int ci = i / 3, k = i % 3;
        swt[i] = TR ? K[((size_t)ci * Cout + co) * 3 + (2 - k)]
                    : K[((size_t)co * Cin + ci) * 3 + k];
    }
    __syncthreads();

    const float* mrow = mask + (size_t)b * N;
    float* orow = xc + ((size_t)b * Cout + co) * N;
    for (int n = tid; n < N; n += blockDim.x) {
        float acc = 0.f;
        const float* zr = z + (size_t)b * Cin * N + n;
        for (int ci = 0; ci < Cin; ++ci, zr += N) {
            float xm = (n > 0)     ? zr[-1] : 0.f;
            float x0 = zr[0];
            float xp = (n < N - 1) ? zr[1]  : 0.f;
            acc = fmaf(swt[ci * 3 + 0], xm, acc);
            acc = fmaf(swt[ci * 3 + 1], x0, acc);
            acc = fmaf(swt[ci * 3 + 2], xp, acc);
        }
        orow[n] -= HSTEP * acc * mrow[n];
    }
}

// ---------------------------------------------------------------------------
// small utility kernels
// ---------------------------------------------------------------------------
__global__ void row_sum_kernel(const float* __restrict__ m, float* __restrict__ denom, int N)
{
    __shared__ float sred[8];
    int b = blockIdx.x;
    float s = 0.f;
    for (int n = threadIdx.x; n < N; n += blockDim.x) s += m[(size_t)b * N + n];
    float tot = block_sum(s, sred);
    if (threadIdx.x == 0) denom[b] = tot;
}

__global__ void pool_mask_kernel(const float* __restrict__ mi, float* __restrict__ mo,
                                 int B, int Nin, int Nout)
{
    int idx = blockIdx.x * blockDim.x + threadIdx.x;
    if (idx >= B * Nout) return;
    int b = idx / Nout, n = idx % Nout;
    float s = mi[(size_t)b * Nin + 2 * n];
    if (2 * n - 1 >= 0)  s += mi[(size_t)b * Nin + 2 * n - 1];
    if (2 * n + 1 < Nin) s += mi[(size_t)b * Nin + 2 * n + 1];
    mo[idx] = (s * (1.f / 3.f) >= 0.5f) ? 1.f : 0.f;
}

__global__ void pool_x_kernel(const float* __restrict__ xin, float* __restrict__ xout,
                              const float* __restrict__ mnew, int C, int Nin, int Nout, int B)
{
    int idx = blockIdx.x * blockDim.x + threadIdx.x;
    if (idx >= B * C * Nout) return;
    int n  = idx % Nout;
    int bc = idx / Nout;
    int b  = bc / C;
    const float* r = xin + (size_t)bc * Nin;
    float s = r[2 * n];
    if (2 * n - 1 >= 0)  s += r[2 * n - 1];
    if (2 * n + 1 < Nin) s += r[2 * n + 1];
    xout[idx] = s * (1.f / 3.f) * mnew[(size_t)b * Nout + n];
}

__global__ void upsample_kernel(const float* __restrict__ xin, float* __restrict__ xout,
                                const float* __restrict__ mask, int C, int Nout, int B)
{
    int idx = blockIdx.x * blockDim.x + threadIdx.x;
    if (idx >= B * C * Nout) return;
    int n  = idx % Nout;
    int bc = idx / Nout;
    int b  = bc / C;
    xout[idx] = xin[(size_t)bc * (Nout / 2) + (n >> 1)] * mask[(size_t)b * Nout + n];
}

// final 1-wide conv (3,32,1) * mask, then coords override where flag==1
__global__ void final_w_kernel(const float* __restrict__ xc, const float* __restrict__ x,
                               const float* __restrict__ W, const float* __restrict__ mask,
                               float* __restrict__ XC, int B, int N)
{
    int idx = blockIdx.x * blockDim.x + threadIdx.x;
    if (idx >= B * N) return;
    int b = idx / N, n = idx % N;
    float mk = mask[idx];
    float fl = x[((size_t)b * 24 + 23) * N + n];
    for (int c = 0; c < 3; ++c) {
        float acc = 0.f;
        for (int ci = 0; ci < 32; ++ci)
            acc = fmaf(W[c * 32 + ci], xc[((size_t)b * 32 + ci) * N + n], acc);
        float v = acc * mk;
        if (fl == 1.f) v = x[((size_t)b * 24 + 20 + c) * N + n];
        XC[((size_t)b * 3 + c) * N + n] = v;
    }
}

// ---------------------------------------------------------------------------
// dist_constraint: prep (flags + normalized deltas), serial scans, combine
// ---------------------------------------------------------------------------
__global__ void dc_prep_kernel(const float* __restrict__ XC, const float* __restrict__ x,
                               const float* __restrict__ mask, float* __restrict__ F,
                               float* __restrict__ DXN, int B, int N)
{
    int idx = blockIdx.x * blockDim.x + threadIdx.x;
    if (idx >= B * N) return;
    int b = idx / N, n = idx % N;
    F[idx] = (x[((size_t)b * 24 + 23) * N + n] == 1.f) ? 1.f : 0.f;
    if (n < N - 1) {
        float dx0 = XC[((size_t)b * 3 + 0) * N + n + 1] - XC[((size_t)b * 3 + 0) * N + n];
        float dx1 = XC[((size_t)b * 3 + 1) * N + n + 1] - XC[((size_t)b * 3 + 1) * N + n];
        float dx2 = XC[((size_t)b * 3 + 2) * N + n + 1] - XC[((size_t)b * 3 + 2) * N + n];
        float d   = dx0 * dx0 + dx1 * dx1 + dx2 * dx2;
        float m0  = mask[idx], m1 = mask[idx + 1];
        bool avM  = floorf((m0 + m1) * 0.5f) < 0.5f;
        float scale = avM ? 0.f : (DCF / sqrtf(d));
        DXN[((size_t)b * 3 + 0) * N + n] = dx0 * scale;
        DXN[((size_t)b * 3 + 1) * N + n] = dx1 * scale;
        DXN[((size_t)b * 3 + 2) * N + n] = dx2 * scale;
    }
}

__global__ void __launch_bounds__(128)
dc_scan_kernel(const float* __restrict__ X, const float* __restrict__ F,
               const float* __restrict__ D, float* __restrict__ XL, float* __restrict__ XR,
               float* __restrict__ WL, float* __restrict__ WR, int N)
{
    __shared__ float sX[3][2048];
    __shared__ float sD[3][2048];
    __shared__ float sF[2048];
    int b = blockIdx.x;
    for (int n = threadIdx.x; n < N; n += blockDim.x) {
        sF[n] = F[(size_t)b * N + n];
        for (int c = 0; c < 3; ++c) {
            sX[c][n] = X[((size_t)b * 3 + c) * N + n];
            sD[c][n] = (n < N - 1) ? D[((size_t)b * 3 + c) * N + n] : 0.f;
        }
    }
    __syncthreads();

    if (threadIdx.x == 0) {           // left scan
        float v0 = sX[0][0], v1 = sX[1][0], v2 = sX[2][0];
        bool seen = sF[0] != 0.f;
        float wl = seen ? 0.f : BIGF;
        XL[((size_t)b * 3 + 0) * N] = v0;
        XL[((size_t)b * 3 + 1) * N] = v1;
        XL[((size_t)b * 3 + 2) * N] = v2;
        WL[(size_t)b * N] = wl;
        for (int j = 1; j < N; ++j) {
            bool fj = sF[j] != 0.f;
            if (fj || !seen) { v0 = sX[0][j]; v1 = sX[1][j]; v2 = sX[2][j]; }
            else             { v0 += sD[0][j - 1]; v1 += sD[1][j - 1]; v2 += sD[2][j - 1]; }
            seen = seen || fj;
            wl = fj ? 0.f : (wl + 1.f);
            XL[((size_t)b * 3 + 0) * N + j] = v0;
            XL[((size_t)b * 3 + 1) * N + j] = v1;
            XL[((size_t)b * 3 + 2) * N + j] = v2;
            WL[(size_t)b * N + j] = wl;
        }
    } else if (threadIdx.x == 64) {   // right scan (separate wave)
        float v0 = sX[0][N - 1], v1 = sX[1][N - 1], v2 = sX[2][N - 1];
        bool seen = sF[N - 1] != 0.f;
        float wr = seen ? 0.f : BIGF;
        XR[((size_t)b * 3 + 0) * N + N - 1] = v0;
        XR[((size_t)b * 3 + 1) * N + N - 1] = v1;
        XR[((size_t)b * 3 + 2) * N + N - 1] = v2;
        WR[(size_t)b * N + N - 1] = wr;
        for (int j = N - 2; j >= 0; --j) {
            bool fj = sF[j] != 0.f;
            if (fj || !seen) { v0 = sX[0][j]; v1 = sX[1][j]; v2 = sX[2][j]; }
            else             { v0 -= sD[0][j]; v1 -= sD[1][j]; v2 -= sD[2][j]; }
            seen = seen || fj;
            wr = fj ? 0.f : (wr + 1.f);
            XR[((size_t)b * 3 + 0) * N + j] = v0;
            XR[((size_t)b * 3 + 1) * N + j] = v1;
            XR[((size_t)b * 3 + 2) * N + j] = v2;
            WR[(size_t)b * N + j] = wr;
        }
    }
}

__global__ void dc_combine_kernel(const float* __restrict__ XL, const float* __restrict__ XR,
                                  const float* __restrict__ WL, const float* __restrict__ WR,
                                  const float* __restrict__ mask, float* __restrict__ XOUT,
                                  float* __restrict__ outx, int B, int N)
{
    int idx = blockIdx.x * blockDim.x + threadIdx.x;
    if (idx >= B * N) return;
    int b = idx / N, n = idx % N;
    float wl = WL[idx], wr = WR[idx];
    float ws = wl + wr;
    float cl, cr;
    if (ws == 0.f) { cl = 0.5f; cr = 0.5f; }
    else           { cl = wr / ws; cr = wl / ws; }
    float mk = mask[idx];
    for (int c = 0; c < 3; ++c) {
        size_t ii = ((size_t)b * 3 + c) * N + n;
        float v = (XL[ii] * cl + XR[ii] * cr) * mk;
        XOUT[ii] = v;
        outx[ii] = v;
    }
}

// ---------------------------------------------------------------------------
// pairwise distances: dists[b,i,j] = sqrt(||y_i - y_j||^2 + 1e-8)
// (centering is a constant shift -> cancels in differences)
// ---------------------------------------------------------------------------
__global__ void __launch_bounds__(256)
tr2dist_kernel(const float* __restrict__ Y, float* __restrict__ out, int B, int N)
{
    int i = blockIdx.x % N;
    int b = blockIdx.x / N;
    const float* yb = Y + (size_t)b * 3 * N;
    float y0 = yb[i], y1 = yb[N + i], y2 = yb[2 * N + i];
    float* orow = out + ((size_t)b * N + i) * N;
    for (int j = threadIdx.x; j < N; j += blockDim.x) {
        float d0 = y0 - yb[j];
        float d1 = y1 - yb[N + j];
        float d2 = y2 - yb[2 * N + j];
        orow[j] = sqrtf(fmaf(d0, d0, fmaf(d1, d1, d2 * d2)) + 1e-8f);
    }
}

// ---------------------------------------------------------------------------
// launch
// ---------------------------------------------------------------------------
extern "C" void kernel_launch(void* const* d_in, const int* in_sizes, int n_in,
                              void* d_out, int out_size, void* d_ws, size_t ws_size,
                              hipStream_t stream)
{
    const float* x    = (const float*)d_in[0];
    const float* mask = (const float*)d_in[1];
    const float* K0   = (const float*)d_in[2];
    const float* K1   = (const float*)d_in[3];
    const float* K2   = (const float*)d_in[4];
    const float* K3   = (const float*)d_in[5];
    const float* K4   = (const float*)d_in[6];
    const float* K5   = (const float*)d_in[7];
    const float* K6   = (const float*)d_in[8];
    const float* W    = (const float*)d_in[9];
    float* out = (float*)d_out;
    float* ws  = (float*)d_ws;

    const int B = 8, N = 2048;
    size_t off = 0;
    auto alloc = [&](size_t nf) { float* p = ws + off; off += nf; return p; };

    float* M1   = alloc((size_t)B * 1024);
    float* M2   = alloc((size_t)B * 512);
    float* DEN0 = alloc(8);
    float* DEN1 = alloc(8);
    float* DEN2 = alloc(8);
    float* BUF0 = alloc(1048576);
    float* BUF1 = alloc(1048576);
    float* BUF2 = alloc(1048576);
    float* BUF3 = alloc(1048576);
    float* XC   = alloc((size_t)B * 3 * N);
    float* Ff   = alloc((size_t)B * N);
    float* DXN  = alloc((size_t)B * 3 * N);
    float* XL   = alloc((size_t)B * 3 * N);
    float* XR   = alloc((size_t)B * 3 * N);
    float* WLb  = alloc((size_t)B * N);
    float* WRb  = alloc((size_t)B * N);
    float* XOUT = alloc((size_t)B * 3 * N);
    (void)ws_size; (void)in_sizes; (void)n_in; (void)out_size;

    auto cdiv = [](int a, int b_) { return (a + b_ - 1) / b_; };

    // masks + denominators
    row_sum_kernel<<<8, 256, 0, stream>>>(mask, DEN0, 2048);
    pool_mask_kernel<<<cdiv(B * 1024, 256), 256, 0, stream>>>(mask, M1, B, 2048, 1024);
    row_sum_kernel<<<8, 256, 0, stream>>>(M1, DEN1, 1024);
    pool_mask_kernel<<<cdiv(B * 512, 256), 256, 0, stream>>>(M1, M2, B, 1024, 512);
    row_sum_kernel<<<8, 256, 0, stream>>>(M2, DEN2, 512);

    // layer 0
    conv_in_relu_kernel<false><<<B * 32, 256, 0, stream>>>(x, BUF0, K0, 24, 32, 2048, mask, DEN0, nullptr);

    // down i=1 (K1), i=2 (K2): residual
    conv_in_relu_kernel<false><<<B * 32, 256, 0, stream>>>(BUF0, BUF1, K1, 32, 32, 2048, mask, DEN0, nullptr);
    conv_axpy_kernel<true><<<B * 32, 256, 0, stream>>>(BUF1, BUF0, K1, 32, 32, 2048, mask);
    conv_in_relu_kernel<false><<<B * 32, 256, 0, stream>>>(BUF0, BUF1, K2, 32, 32, 2048, mask, DEN0, nullptr);
    conv_axpy_kernel<true><<<B * 32, 256, 0, stream>>>(BUF1, BUF0, K2, 32, 32, 2048, mask);

    // down i=3 (K3, 32->64) + pool   (BUF0 preserved as skip xS0)
    conv_in_relu_kernel<false><<<B * 64, 256, 0, stream>>>(BUF0, BUF1, K3, 32, 64, 2048, mask, DEN0, nullptr);
    pool_x_kernel<<<cdiv(B * 64 * 1024, 256), 256, 0, stream>>>(BUF1, BUF2, M1, 64, 2048, 1024, B);

    // down i=4 (K4), i=5 (K5): residual @1024
    conv_in_relu_kernel<false><<<B * 64, 256, 0, stream>>>(BUF2, BUF1, K4, 64, 64, 1024, M1, DEN1, nullptr);
    conv_axpy_kernel<true><<<B * 64, 256, 0, stream>>>(BUF1, BUF2, K4, 64, 64, 1024, M1);
    conv_in_relu_kernel<false><<<B * 64, 256, 0, stream>>>(BUF2, BUF1, K5, 64, 64, 1024, M1, DEN1, nullptr);
    conv_axpy_kernel<true><<<B * 64, 256, 0, stream>>>(BUF1, BUF2, K5, 64, 64, 1024, M1);

    // down i=6 (K6, 64->128) + pool  (BUF2 preserved as skip xS1)
    conv_in_relu_kernel<false><<<B * 128, 256, 0, stream>>>(BUF2, BUF1, K6, 64, 128, 1024, M1, DEN1, nullptr);
    pool_x_kernel<<<cdiv(B * 128 * 512, 256), 256, 0, stream>>>(BUF1, BUF3, M2, 128, 1024, 512, B);

    // up i=6: upsample 512->1024, convT K6 (128->64) + IN + relu + skip(BUF2)
    upsample_kernel<<<cdiv(B * 128 * 1024, 256), 256, 0, stream>>>(BUF3, BUF1, M1, 128, 1024, B);
    conv_in_relu_kernel<true><<<B * 64, 256, 0, stream>>>(BUF1, BUF3, K6, 128, 64, 1024, M1, DEN1, BUF2);

    // up i=5 (K5), i=4 (K4): residual with convT then conv
    conv_in_relu_kernel<true><<<B * 64, 256, 0, stream>>>(BUF3, BUF1, K5, 64, 64, 1024, M1, DEN1, nullptr);
    conv_axpy_kernel<false><<<B * 64, 256, 0, stream>>>(BUF1, BUF3, K5, 64, 64, 1024, M1);
    conv_in_relu_kernel<true><<<B * 64, 256, 0, stream>>>(BUF3, BUF1, K4, 64, 64, 1024, M1, DEN1, nullptr);
    conv_axpy_kernel<false><<<B * 64, 256, 0, stream>>>(BUF1, BUF3, K4, 64, 64, 1024, M1);

    // up i=3: upsample 1024->2048, convT K3 (64->32) + IN + relu + skip(BUF0)
    upsample_kernel<<<cdiv(B * 64 * 2048, 256), 256, 0, stream>>>(BUF3, BUF1, mask, 64, 2048, B);
    conv_in_relu_kernel<true><<<B * 32, 256, 0, stream>>>(BUF1, BUF2, K3, 64, 32, 2048, mask, DEN0, BUF0);

    // up i=2 (K2), i=1 (K1): residual
    conv_in_relu_kernel<true><<<B * 32, 256, 0, stream>>>(BUF2, BUF1, K2, 32, 32, 2048, mask, DEN0, nullptr);
    conv_axpy_kernel<false><<<B * 32, 256, 0, stream>>>(BUF1, BUF2, K2, 32, 32, 2048, mask);
    conv_in_relu_kernel<true><<<B * 32, 256, 0, stream>>>(BUF2, BUF1, K1, 32, 32, 2048, mask, DEN0, nullptr);
    conv_axpy_kernel<false><<<B * 32, 256, 0, stream>>>(BUF1, BUF2, K1, 32, 32, 2048, mask);

    // final 1x conv + coords override
    final_w_kernel<<<cdiv(B * N, 256), 256, 0, stream>>>(BUF2, x, W, mask, XC, B, N);

    // dist_constraint
    dc_prep_kernel<<<cdiv(B * N, 256), 256, 0, stream>>>(XC, x, mask, Ff, DXN, B, N);
    dc_scan_kernel<<<B, 128, 0, stream>>>(XC, Ff, DXN, XL, XR, WLb, WRb, N);
    dc_combine_kernel<<<cdiv(B * N, 256), 256, 0, stream>>>(XL, XR, WLb, WRb, mask, XOUT,
                                                            out + (size_t)B * N * N, B, N);

    // pairwise distance matrix
    tr2dist_kernel<<<B * N, 256, 0, stream>>>(XOUT, out, B, N);
}

// Round 2
// 422.418 us; speedup vs baseline: 2.8349x; 2.8349x over previous
//
#include <hip/hip_runtime.h>
#include <math.h>

#define HSTEP 0.1f
#define EPS_IN 1e-5f
#define BIGF 1e10f
#define DCF 3.79f

// ---------------------------------------------------------------------------
// helpers
// ---------------------------------------------------------------------------
__device__ inline float block_sum1(float v, float* sred) {
    #pragma unroll
    for (int off = 32; off > 0; off >>= 1) v += __shfl_down(v, off);
    int wid = threadIdx.x >> 6;
    int nw  = blockDim.x >> 6;
    if ((threadIdx.x & 63) == 0) sred[wid] = v;
    __syncthreads();
    float total = 0.f;
    for (int i = 0; i < nw; ++i) total += sred[i];
    __syncthreads();
    return total;
}

__device__ inline float2 block_sum2(float a, float b, float2* sred) {
    #pragma unroll
    for (int off = 32; off > 0; off >>= 1) {
        a += __shfl_down(a, off);
        b += __shfl_down(b, off);
    }
    int wid = threadIdx.x >> 6;
    int nw  = blockDim.x >> 6;
    if ((threadIdx.x & 63) == 0) sred[wid] = make_float2(a, b);
    __syncthreads();
    float ta = 0.f, tb = 0.f;
    for (int i = 0; i < nw; ++i) { ta += sred[i].x; tb += sred[i].y; }
    __syncthreads();
    return make_float2(ta, tb);
}

// ---------------------------------------------------------------------------
// fused conv (optionally transposed weights) * mask -> masked instance norm
// -> relu -> optional skip add.  One block (1024 thr = 16 waves) per (b, co).
// ---------------------------------------------------------------------------
template<int CIN, bool TR>
__global__ void __launch_bounds__(1024)
conv_in_relu_kernel(const float* __restrict__ xin, float* __restrict__ out,
                    const float* __restrict__ K, int Cout, int N,
                    const float* __restrict__ mask, const float* __restrict__ denom,
                    const float* __restrict__ skip)
{
    __shared__ float srow[2048];
    __shared__ float swt[CIN * 3];
    __shared__ float2 sred[16];

    const int b   = blockIdx.x / Cout;
    const int co  = blockIdx.x % Cout;
    const int tid = threadIdx.x;

    for (int i = tid; i < CIN * 3; i += blockDim.x) {
        int ci = i / 3, k = i % 3;
        swt[i] = TR ? K[((size_t)ci * Cout + co) * 3 + (2 - k)]
                    : K[((size_t)co * CIN + ci) * 3 + k];
    }
    __syncthreads();

    const float* mrow = mask + (size_t)b * N;
    const float* xb   = xin + (size_t)b * CIN * N;
    float lsum = 0.f, lss = 0.f;
    for (int n = tid; n < N; n += 1024) {
        float acc = 0.f;
        const float* xr = xb + n;
        #pragma unroll 8
        for (int ci = 0; ci < CIN; ++ci, xr += N) {
            float xm = (n > 0)     ? xr[-1] : 0.f;
            float x0 = xr[0];
            float xp = (n < N - 1) ? xr[1]  : 0.f;
            acc = fmaf(swt[ci * 3 + 0], xm, acc);
            acc = fmaf(swt[ci * 3 + 1], x0, acc);
            acc = fmaf(swt[ci * 3 + 2], xp, acc);
        }
        float v = acc * mrow[n];
        srow[n] = v;
        lsum += v;
        lss  += v * v;
    }
    float dn = denom[b];
    float2 s = block_sum2(lsum, lss, sred);
    float mean = s.x / dn;
    float var  = s.y / dn - mean * mean;
    float inv  = 1.f / sqrtf(var + EPS_IN);

    float* orow = out + ((size_t)b * Cout + co) * N;
    const float* skrow = skip ? skip + ((size_t)b * Cout + co) * N : nullptr;
    for (int n = tid; n < N; n += 1024) {
        float mk = mrow[n];
        float zv = (srow[n] - mean * mk) * inv;
        float r  = fmaxf(zv, 0.f);
        if (skrow) r += skrow[n];
        orow[n] = r;
    }
}

// ---------------------------------------------------------------------------
// residual update: xc -= HSTEP * conv(z) * mask
// ---------------------------------------------------------------------------
template<int CIN, bool TR>
__global__ void __launch_bounds__(1024)
conv_axpy_kernel(const float* __restrict__ z, float* __restrict__ xc,
                 const float* __restrict__ K, int Cout, int N,
                 const float* __restrict__ mask)
{
    __shared__ float swt[CIN * 3];
    const int b   = blockIdx.x / Cout;
    const int co  = blockIdx.x % Cout;
    const int tid = threadIdx.x;

    for (int i = tid; i < CIN * 3; i += blockDim.x) {
        int ci = i / 3, k = i % 3;
        swt[i] = TR ? K[((size_t)ci * Cout + co) * 3 + (2 - k)]
                    : K[((size_t)co * CIN + ci) * 3 + k];
    }
    __syncthreads();

    const float* mrow = mask + (size_t)b * N;
    const float* zb   = z + (size_t)b * CIN * N;
    float* orow = xc + ((size_t)b * Cout + co) * N;
    for (int n = tid; n < N; n += 1024) {
        float acc = 0.f;
        const float* zr = zb + n;
        #pragma unroll 8
        for (int ci = 0; ci < CIN; ++ci, zr += N) {
            float xm = (n > 0)     ? zr[-1] : 0.f;
            float x0 = zr[0];
            float xp = (n < N - 1) ? zr[1]  : 0.f;
            acc = fmaf(swt[ci * 3 + 0], xm, acc);
            acc = fmaf(swt[ci * 3 + 1], x0, acc);
            acc = fmaf(swt[ci * 3 + 2], xp, acc);
        }
        orow[n] -= HSTEP * acc * mrow[n];
    }
}

// ---------------------------------------------------------------------------
// fused mask pipeline: DEN0, M1, DEN1, M2 in one kernel (block per b)
// ---------------------------------------------------------------------------
__global__ void __launch_bounds__(256)
mask_prep_kernel(const float* __restrict__ mask, float* __restrict__ M1,
                 float* __restrict__ M2, float* __restrict__ d0, float* __restrict__ d1)
{
    __shared__ float sm1[1024];
    __shared__ float sredf[4];
    int b = blockIdx.x, tid = threadIdx.x;
    const float* mr = mask + (size_t)b * 2048;

    float s0 = 0.f;
    for (int n = tid; n < 2048; n += 256) s0 += mr[n];
    float t0 = block_sum1(s0, sredf);
    if (tid == 0) d0[b] = t0;

    for (int n = tid; n < 1024; n += 256) {
        float s = mr[2 * n];
        if (2 * n - 1 >= 0)   s += mr[2 * n - 1];
        if (2 * n + 1 < 2048) s += mr[2 * n + 1];
        float v = (s * (1.f / 3.f) >= 0.5f) ? 1.f : 0.f;
        sm1[n] = v;
        M1[(size_t)b * 1024 + n] = v;
    }
    __syncthreads();
    float s1 = 0.f;
    for (int n = tid; n < 1024; n += 256) s1 += sm1[n];
    float t1 = block_sum1(s1, sredf);
    if (tid == 0) d1[b] = t1;

    for (int n = tid; n < 512; n += 256) {
        float s = sm1[2 * n];
        if (2 * n - 1 >= 0)   s += sm1[2 * n - 1];
        if (2 * n + 1 < 1024) s += sm1[2 * n + 1];
        M2[(size_t)b * 512 + n] = (s * (1.f / 3.f) >= 0.5f) ? 1.f : 0.f;
    }
}

// ---------------------------------------------------------------------------
// pooling / upsampling
// ---------------------------------------------------------------------------
__global__ void pool_x_kernel(const float* __restrict__ xin, float* __restrict__ xout,
                              const float* __restrict__ mnew, int C, int Nin, int Nout, int B)
{
    int idx = blockIdx.x * blockDim.x + threadIdx.x;
    if (idx >= B * C * Nout) return;
    int n  = idx % Nout;
    int bc = idx / Nout;
    int b  = bc / C;
    const float* r = xin + (size_t)bc * Nin;
    float s = r[2 * n];
    if (2 * n - 1 >= 0)  s += r[2 * n - 1];
    if (2 * n + 1 < Nin) s += r[2 * n + 1];
    xout[idx] = s * (1.f / 3.f) * mnew[(size_t)b * Nout + n];
}

__global__ void upsample_kernel(const float* __restrict__ xin, float* __restrict__ xout,
                                const float* __restrict__ mask, int C, int Nout, int B)
{
    int idx = blockIdx.x * blockDim.x + threadIdx.x;
    if (idx >= B * C * Nout) return;
    int n  = idx % Nout;
    int bc = idx / Nout;
    int b  = bc / C;
    xout[idx] = xin[(size_t)bc * (Nout / 2) + (n >> 1)] * mask[(size_t)b * Nout + n];
}

// ---------------------------------------------------------------------------
// fused: final W conv + coords override + dist_constraint (prep/scan/combine)
// One block (1024 thr) per batch.  Segmented scan parallelized: each thread
// finds its segment's fixed point via ballot bitmasks and replays the exact
// sequential fp32 accumulation (expected segment length ~2).
// ---------------------------------------------------------------------------
__global__ void __launch_bounds__(1024)
dc_all_kernel(const float* __restrict__ xc32, const float* __restrict__ x,
              const float* __restrict__ W, const float* __restrict__ mask,
              const float* __restrict__ den, float* __restrict__ xout, int N)
{
    __shared__ float sX[3][2048];
    __shared__ float sD[3][2048];
    __shared__ float sM[2048];
    __shared__ unsigned long long smk[32];
    __shared__ float sW[96];

    const int b = blockIdx.x, tid = threadIdx.x;
    if (tid < 96) sW[tid] = W[tid];
    __syncthreads();

    const float* xb      = xc32 + (size_t)b * 32 * N;
    const float* flagrow = x + ((size_t)b * 24 + 23) * N;

    #pragma unroll
    for (int r = 0; r < 2; ++r) {
        int n = tid + r * 1024;
        float mk = mask[(size_t)b * N + n];
        float fl = flagrow[n];
        float v0 = 0.f, v1 = 0.f, v2 = 0.f;
        #pragma unroll 8
        for (int ci = 0; ci < 32; ++ci) {
            float xv = xb[(size_t)ci * N + n];
            v0 = fmaf(sW[0 * 32 + ci], xv, v0);
            v1 = fmaf(sW[1 * 32 + ci], xv, v1);
            v2 = fmaf(sW[2 * 32 + ci], xv, v2);
        }
        v0 *= mk; v1 *= mk; v2 *= mk;
        bool fixed = (fl == 1.f);
        if (fixed) {
            v0 = x[((size_t)b * 24 + 20) * N + n];
            v1 = x[((size_t)b * 24 + 21) * N + n];
            v2 = x[((size_t)b * 24 + 22) * N + n];
        }
        sX[0][n] = v0; sX[1][n] = v1; sX[2][n] = v2; sM[n] = mk;
        unsigned long long bm = __ballot(fixed);
        if ((tid & 63) == 0) smk[n >> 6] = bm;
    }
    __syncthreads();

    // normalized deltas (exact reference formula)
    #pragma unroll
    for (int r = 0; r < 2; ++r) {
        int n = tid + r * 1024;
        if (n < N - 1) {
            float d0 = sX[0][n + 1] - sX[0][n];
            float d1 = sX[1][n + 1] - sX[1][n];
            float d2 = sX[2][n + 1] - sX[2][n];
            float d  = d0 * d0 + d1 * d1 + d2 * d2;
            bool avM = floorf((sM[n] + sM[n + 1]) * 0.5f) < 0.5f;
            if (avM) {
                sD[0][n] = 0.f; sD[1][n] = 0.f; sD[2][n] = 0.f;
            } else {
                float sq = sqrtf(d);
                sD[0][n] = (d0 / sq) * DCF;
                sD[1][n] = (d1 / sq) * DCF;
                sD[2][n] = (d2 / sq) * DCF;
            }
        }
    }
    __syncthreads();

    int len = (int)den[b];

    #pragma unroll
    for (int r = 0; r < 2; ++r) {
        int j  = tid + r * 1024;
        int cc = j >> 6, jl = j & 63;

        // left: last fixed index p <= j
        unsigned long long below = smk[cc] & (~0ull >> (63 - jl));
        int p = -1;
        if (below) p = (cc << 6) + 63 - __clzll(below);
        else {
            for (int c2 = cc - 1; c2 >= 0; --c2) {
                unsigned long long m = smk[c2];
                if (m) { p = (c2 << 6) + 63 - __clzll(m); break; }
            }
        }
        float l0, l1, l2, wl;
        if (p >= 0) {
            wl = (float)(j - p);
            l0 = sX[0][p]; l1 = sX[1][p]; l2 = sX[2][p];
            int kend = min(j, len - 1);
            for (int k = p; k < kend; ++k) {
                l0 += sD[0][k]; l1 += sD[1][k]; l2 += sD[2][k];
            }
        } else { wl = BIGF; l0 = sX[0][j]; l1 = sX[1][j]; l2 = sX[2][j]; }

        // right: next fixed index q >= j
        unsigned long long above = smk[cc] & (~0ull << jl);
        int q = -1;
        if (above) q = (cc << 6) + __ffsll((unsigned long long)above) - 1;
        else {
            for (int c2 = cc + 1; c2 < 32; ++c2) {
                unsigned long long m = smk[c2];
                if (m) { q = (c2 << 6) + __ffsll((unsigned long long)m) - 1; break; }
            }
        }
        float r0, r1, r2, wr;
        if (q >= 0) {
            wr = (float)(q - j);
            r0 = sX[0][q]; r1 = sX[1][q]; r2 = sX[2][q];
            for (int k = q - 1; k >= j; --k) {
                r0 -= sD[0][k]; r1 -= sD[1][k]; r2 -= sD[2][k];
            }
        } else { wr = BIGF; r0 = sX[0][j]; r1 = sX[1][j]; r2 = sX[2][j]; }

        float ws_ = wl + wr;
        float cl, cr;
        if (ws_ == 0.f) { cl = 0.5f; cr = 0.5f; }
        else            { cl = wr / ws_; cr = wl / ws_; }
        float mk = sM[j];
        xout[((size_t)b * 3 + 0) * N + j] = (l0 * cl + r0 * cr) * mk;
        xout[((size_t)b * 3 + 1) * N + j] = (l1 * cl + r1 * cr) * mk;
        xout[((size_t)b * 3 + 2) * N + j] = (l2 * cl + r2 * cr) * mk;
    }
}

// ---------------------------------------------------------------------------
// pairwise distances
// ---------------------------------------------------------------------------
__global__ void __launch_bounds__(256)
tr2dist_kernel(const float* __restrict__ Y, float* __restrict__ out, int B, int N)
{
    int i = blockIdx.x % N;
    int b = blockIdx.x / N;
    const float* yb = Y + (size_t)b * 3 * N;
    float y0 = yb[i], y1 = yb[N + i], y2 = yb[2 * N + i];
    float* orow = out + ((size_t)b * N + i) * N;
    for (int j = threadIdx.x; j < N; j += blockDim.x) {
        float d0 = y0 - yb[j];
        float d1 = y1 - yb[N + j];
        float d2 = y2 - yb[2 * N + j];
        orow[j] = sqrtf(fmaf(d0, d0, fmaf(d1, d1, d2 * d2)) + 1e-8f);
    }
}

// ---------------------------------------------------------------------------
// launch
// ---------------------------------------------------------------------------
extern "C" void kernel_launch(void* const* d_in, const int* in_sizes, int n_in,
                              void* d_out, int out_size, void* d_ws, size_t ws_size,
                              hipStream_t stream)
{
    const float* x    = (const float*)d_in[0];
    const float* mask = (const float*)d_in[1];
    const float* K0   = (const float*)d_in[2];
    const float* K1   = (const float*)d_in[3];
    const float* K2   = (const float*)d_in[4];
    const float* K3   = (const float*)d_in[5];
    const float* K4   = (const float*)d_in[6];
    const float* K5   = (const float*)d_in[7];
    const float* K6   = (const float*)d_in[8];
    const float* W    = (const float*)d_in[9];
    float* out = (float*)d_out;
    float* ws  = (float*)d_ws;

    const int B = 8, N = 2048;
    size_t off = 0;
    auto alloc = [&](size_t nf) { float* p = ws + off; off += nf; return p; };

    float* M1   = alloc((size_t)B * 1024);
    float* M2   = alloc((size_t)B * 512);
    float* DEN0 = alloc(8);
    float* DEN1 = alloc(8);
    float* BUF0 = alloc(1048576);
    float* BUF1 = alloc(1048576);
    float* BUF2 = alloc(1048576);
    float* BUF3 = alloc(1048576);
    (void)ws_size; (void)in_sizes; (void)n_in; (void)out_size;

    auto cdiv = [](int a, int b_) { return (a + b_ - 1) / b_; };
    float* XOUT = out + (size_t)B * N * N;   // xout section of output

    // masks + denominators (fused)
    mask_prep_kernel<<<8, 256, 0, stream>>>(mask, M1, M2, DEN0, DEN1);

    // layer 0
    conv_in_relu_kernel<24, false><<<B * 32, 1024, 0, stream>>>(x, BUF0, K0, 32, 2048, mask, DEN0, nullptr);

    // down i=1 (K1), i=2 (K2): residual
    conv_in_relu_kernel<32, false><<<B * 32, 1024, 0, stream>>>(BUF0, BUF1, K1, 32, 2048, mask, DEN0, nullptr);
    conv_axpy_kernel<32, true><<<B * 32, 1024, 0, stream>>>(BUF1, BUF0, K1, 32, 2048, mask);
    conv_in_relu_kernel<32, false><<<B * 32, 1024, 0, stream>>>(BUF0, BUF1, K2, 32, 2048, mask, DEN0, nullptr);
    conv_axpy_kernel<32, true><<<B * 32, 1024, 0, stream>>>(BUF1, BUF0, K2, 32, 2048, mask);

    // down i=3 (K3, 32->64) + pool   (BUF0 preserved as skip xS0)
    conv_in_relu_kernel<32, false><<<B * 64, 1024, 0, stream>>>(BUF0, BUF1, K3, 64, 2048, mask, DEN0, nullptr);
    pool_x_kernel<<<cdiv(B * 64 * 1024, 256), 256, 0, stream>>>(BUF1, BUF2, M1, 64, 2048, 1024, B);

    // down i=4 (K4), i=5 (K5): residual @1024
    conv_in_relu_kernel<64, false><<<B * 64, 1024, 0, stream>>>(BUF2, BUF1, K4, 64, 1024, M1, DEN1, nullptr);
    conv_axpy_kernel<64, true><<<B * 64, 1024, 0, stream>>>(BUF1, BUF2, K4, 64, 1024, M1);
    conv_in_relu_kernel<64, false><<<B * 64, 1024, 0, stream>>>(BUF2, BUF1, K5, 64, 1024, M1, DEN1, nullptr);
    conv_axpy_kernel<64, true><<<B * 64, 1024, 0, stream>>>(BUF1, BUF2, K5, 64, 1024, M1);

    // down i=6 (K6, 64->128) + pool  (BUF2 preserved as skip xS1)
    conv_in_relu_kernel<64, false><<<B * 128, 1024, 0, stream>>>(BUF2, BUF1, K6, 128, 1024, M1, DEN1, nullptr);
    pool_x_kernel<<<cdiv(B * 128 * 512, 256), 256, 0, stream>>>(BUF1, BUF3, M2, 128, 1024, 512, B);

    // up i=6: upsample 512->1024, convT K6 (128->64) + IN + relu + skip(BUF2)
    upsample_kernel<<<cdiv(B * 128 * 1024, 256), 256, 0, stream>>>(BUF3, BUF1, M1, 128, 1024, B);
    conv_in_relu_kernel<128, true><<<B * 64, 1024, 0, stream>>>(BUF1, BUF3, K6, 64, 1024, M1, DEN1, BUF2);

    // up i=5 (K5), i=4 (K4): residual with convT then conv
    conv_in_relu_kernel<64, true><<<B * 64, 1024, 0, stream>>>(BUF3, BUF1, K5, 64, 1024, M1, DEN1, nullptr);
    conv_axpy_kernel<64, false><<<B * 64, 1024, 0, stream>>>(BUF1, BUF3, K5, 64, 1024, M1);
    conv_in_relu_kernel<64, true><<<B * 64, 1024, 0, stream>>>(BUF3, BUF1, K4, 64, 1024, M1, DEN1, nullptr);
    conv_axpy_kernel<64, false><<<B * 64, 1024, 0, stream>>>(BUF1, BUF3, K4, 64, 1024, M1);

    // up i=3: upsample 1024->2048, convT K3 (64->32) + IN + relu + skip(BUF0)
    upsample_kernel<<<cdiv(B * 64 * 2048, 256), 256, 0, stream>>>(BUF3, BUF1, mask, 64, 2048, B);
    conv_in_relu_kernel<64, true><<<B * 32, 1024, 0, stream>>>(BUF1, BUF2, K3, 32, 2048, mask, DEN0, BUF0);

    // up i=2 (K2), i=1 (K1): residual
    conv_in_relu_kernel<32, true><<<B * 32, 1024, 0, stream>>>(BUF2, BUF1, K2, 32, 2048, mask, DEN0, nullptr);
    conv_axpy_kernel<32, false><<<B * 32, 1024, 0, stream>>>(BUF1, BUF2, K2, 32, 2048, mask);
    conv_in_relu_kernel<32, true><<<B * 32, 1024, 0, stream>>>(BUF2, BUF1, K1, 32, 2048, mask, DEN0, nullptr);
    conv_axpy_kernel<32, false><<<B * 32, 1024, 0, stream>>>(BUF1, BUF2, K1, 32, 2048, mask);

    // final W conv + coords override + dist_constraint, all in one kernel
    dc_all_kernel<<<B, 1024, 0, stream>>>(BUF2, x, W, mask, DEN0, XOUT, N);

    // pairwise distance matrix
    tr2dist_kernel<<<B * N, 256, 0, stream>>>(XOUT, out, B, N);
}